// Round 2
// 228.236 us; speedup vs baseline: 1.0002x; 1.0002x over previous
//
#include <hip/hip_runtime.h>
#include <hip/hip_bf16.h>

// Problem constants
#define IN_DIM   256
#define CODE_LEN 128
#define MEM_LEN  65536
#define BETA     1.0f

// Output layout (floats): [0]=loss, [1..]=memory (MEM_LEN*CODE_LEN),
// then mem_data (MEM_LEN*IN_DIM), then mem_idx (MEM_LEN, as float)
#define OUT_MEM_OFF   1
#define OUT_MD_OFF    (1 + MEM_LEN*CODE_LEN)            // 8388609
#define OUT_IDX_OFF   (OUT_MD_OFF + MEM_LEN*IN_DIM)     // 25165825

// Workspace (float indices):
#define WS_COLSUM 0      // float[256]
#define WS_COLSQ  256    // float[256]
#define WS_ENC    512    // float[128]
#define WS_LOSS   640    // uint (init 0xFFFFFFFF)
#define WS_KEY    642    // u64 at byte 2568 (init all-ones)
#define WS_CTR2   644    // uint: stats-kernel completion counter (init 0)

#define MD_ELEMS  (MEM_LEN*IN_DIM)     // 16777216
#define MD_TILES  ((MD_ELEMS-4)/4)     // 4194303 shifted tiles [4k+3..4k+6]
#define MEM_ELEMS (MEM_LEN*CODE_LEN)   // 8388608
#define MEM_STORE_TILES 2097151        // shifted tiles for memory copy

// native clang vector type — required by __builtin_nontemporal_store
typedef float vfloat4 __attribute__((ext_vector_type(4)));

__device__ __forceinline__ vfloat4 load4u(const float* p) {
    vfloat4 v; v.x = p[0]; v.y = p[1]; v.z = p[2]; v.w = p[3]; return v;
}

// ---------------------------------------------------------------------------
// init: zero colsum/colsq, set loss/key sentinels, zero completion counter.
__global__ void k_init(float* __restrict__ ws) {
    const int t = threadIdx.x;            // 64 threads
    #pragma unroll
    for (int j = 0; j < 8; ++j) ws[t + j * 64] = 0.f;   // 512 floats
    if (t == 0) {
        ((unsigned int*)ws)[WS_LOSS] = 0xFFFFFFFFu;
        *((unsigned long long*)(ws + WS_KEY)) = ~0ull;
        ((unsigned int*)ws)[WS_CTR2] = 0u;
    }
}

// ---------------------------------------------------------------------------
// A (+enc fold): blocks [0,1024): copy mem_data -> out (aligned NT f4 stores,
//    shifted tiles, batched 8-deep loads) + per-column sum/sumsq.
//    blocks [1024,1088): mem_idx copy + packed argmin.
//    Last-finishing block (device-scope counter) computes mean/std -> nrm ->
//    enc = nrm @ W^T + b, replacing the old 1-block k_enc dispatch.
//    Ordering: device-scope atomics are performed at the coherent point, so
//    per-thread vmcnt(0) drain + __syncthreads before the counter bump is
//    sufficient (no L2 writeback needed — nothing reads the NT-stored copy
//    data within this kernel).
__global__ __launch_bounds__(256, 4) void k_stats_enc(
        const float* __restrict__ x,
        const float* __restrict__ mem_data,
        const int*   __restrict__ mem_idx,
        const float* __restrict__ W,
        const float* __restrict__ b,
        float* __restrict__ out,
        float* __restrict__ ws) {
    const int t = threadIdx.x;

    if (blockIdx.x >= 1024) {
        __shared__ unsigned long long red[256];
        const int tid = (blockIdx.x - 1024) * 256 + t;      // 0..16383
        unsigned long long local = ~0ull;
        #pragma unroll
        for (int rep = 0; rep < 4; ++rep) {
            int i = tid + rep * 16384;
            int v = mem_idx[i];
            out[OUT_IDX_OFF + i] = (float)v;
            unsigned long long key =
                (((unsigned long long)(unsigned int)(v ^ (int)0x80000000)) << 32)
                | (unsigned int)i;
            local = local < key ? local : key;
        }
        red[t] = local;
        __syncthreads();
        for (int s = 128; s > 0; s >>= 1) {
            if (t < s) { unsigned long long o = red[t + s]; if (o < red[t]) red[t] = o; }
            __syncthreads();
        }
        if (t == 0) atomicMin((unsigned long long*)(ws + WS_KEY), red[0]);
    } else {
        __shared__ float lsum[256], lsq[256];
        float* __restrict__ out_md = out + OUT_MD_OFF;
        const int t0 = blockIdx.x * 256 + t;                    // 0..262143
        float s0=0,s1=0,s2=0,s3=0,q0=0,q1=0,q2=0,q3=0;

        // 16 tiles/thread, stride 262144 (mult of 64 => columns fixed per
        // thread). Two groups of 8: batch loads, then accumulate+NT-stores.
        #pragma unroll
        for (int g = 0; g < 2; ++g) {
            vfloat4 v[8];
            #pragma unroll
            for (int j = 0; j < 8; ++j) {
                const int k = t0 + (g * 8 + j) * 262144;
                if (k < MD_TILES) v[j] = load4u(mem_data + 4*k + 3);
                else              v[j] = (vfloat4){0.f, 0.f, 0.f, 0.f};
            }
            #pragma unroll
            for (int j = 0; j < 8; ++j) {
                const int k = t0 + (g * 8 + j) * 262144;
                if (k < MD_TILES) {
                    __builtin_nontemporal_store(v[j],
                        reinterpret_cast<vfloat4*>(out_md + 4*k + 3));  // 16B-aligned
                    s0 += v[j].x; q0 += v[j].x * v[j].x;
                    s1 += v[j].y; q1 += v[j].y * v[j].y;
                    s2 += v[j].z; q2 += v[j].z * v[j].z;
                    s3 += v[j].w; q3 += v[j].w * v[j].w;
                }
            }
        }

        lsum[t] = 0.f; lsq[t] = 0.f;
        __syncthreads();
        const int c0 = (4*t0 + 3) & 255;
        atomicAdd(&lsum[c0],         s0);  atomicAdd(&lsq[c0],         q0);
        atomicAdd(&lsum[(c0+1)&255], s1);  atomicAdd(&lsq[(c0+1)&255], q1);
        atomicAdd(&lsum[(c0+2)&255], s2);  atomicAdd(&lsq[(c0+2)&255], q2);
        atomicAdd(&lsum[(c0+3)&255], s3);  atomicAdd(&lsq[(c0+3)&255], q3);
        __syncthreads();
        atomicAdd(&ws[WS_COLSUM + t], lsum[t]);
        atomicAdd(&ws[WS_COLSQ  + t], lsq[t]);

        if (blockIdx.x == 0 && t == 0) {
            for (int e = 0; e < 3; ++e) {
                float v = mem_data[e];
                out_md[e] = v;
                atomicAdd(&ws[WS_COLSUM + e], v);
                atomicAdd(&ws[WS_COLSQ  + e], v*v);
            }
            float v = mem_data[MD_ELEMS - 1];
            out_md[MD_ELEMS - 1] = v;
            atomicAdd(&ws[WS_COLSUM + 255], v);
            atomicAdd(&ws[WS_COLSQ  + 255], v*v);
        }
    }

    // ---- completion detection: last of 1088 blocks computes enc ----
    asm volatile("s_waitcnt vmcnt(0)" ::: "memory");  // all own atomics at coherent point
    __syncthreads();                                  // whole block drained
    __shared__ unsigned int s_last;
    if (t == 0)
        s_last = (atomicAdd(&((unsigned int*)ws)[WS_CTR2], 1u) == 1087u) ? 1u : 0u;
    __syncthreads();
    if (!s_last) return;

    // ---- former k_enc, bit-identical arithmetic ----
    __shared__ float nrm[IN_DIM];
    {
        // identity atomics = guaranteed-coherent read of the accumulators
        float sum = atomicAdd(&ws[WS_COLSUM + t], 0.0f);
        float sq  = atomicAdd(&ws[WS_COLSQ  + t], 0.0f);
        float mean = sum * (1.0f / MEM_LEN);
        float var  = (sq - sum * sum * (1.0f / MEM_LEN)) * (1.0f / (MEM_LEN - 1));
        var = fmaxf(var, 0.0f);
        float sd = sqrtf(var);
        nrm[t] = (sd == 0.0f) ? 0.0f : (x[t] - mean) / sd;
    }
    __syncthreads();
    if (t < CODE_LEN) {
        float acc = b[t];
        const float* w = W + t * IN_DIM;
        #pragma unroll 8
        for (int d = 0; d < IN_DIM; ++d) acc += nrm[d] * w[d];
        ws[WS_ENC + t] = acc;
    }
}

// ---------------------------------------------------------------------------
// C: memory copy (aligned NT f4 stores via shifted tiles, L1-hit shifted
//    re-loads) + L1 distance per row (aligned loads), global min.
//    (Unchanged; the epilogue stays a separate dispatch because its scatter
//    overwrites NT-stored lines from other XCDs — the kernel boundary is the
//    cheapest correct cross-XCD flush.)
__global__ __launch_bounds__(256, 4) void k_dist_copy(
        const float* __restrict__ memory,
        float* __restrict__ out,
        float* __restrict__ ws) {
    __shared__ vfloat4 es[32];
    __shared__ float red[256];
    const int t = threadIdx.x;
    if (t < 32) es[t] = ((const vfloat4*)(ws + WS_ENC))[t];
    __syncthreads();
    const int lane = t & 31;
    const int grp  = t >> 5;
    const vfloat4 e = es[lane];
    float* __restrict__ out_al = out + 4;   // region idx 3; 16B-aligned
    float localmin = 3.4e38f;
    #pragma unroll
    for (int half = 0; half < 2; ++half) {
        vfloat4 m[4], s[4];
        int idx[4];
        #pragma unroll
        for (int sw = 0; sw < 4; ++sw) {
            const int row = (half * 4 + sw) * 8192 + blockIdx.x * 8 + grp;
            const int i = row * 32 + lane;
            idx[sw] = i;
            m[sw] = ((const vfloat4*)memory)[i];             // aligned
            s[sw] = (i < MEM_STORE_TILES) ? load4u(memory + 4*i + 3)
                                          : (vfloat4){0.f, 0.f, 0.f, 0.f};
        }
        #pragma unroll
        for (int sw = 0; sw < 4; ++sw) {
            const int i = idx[sw];
            if (i < MEM_STORE_TILES)
                __builtin_nontemporal_store(s[sw],
                    reinterpret_cast<vfloat4*>(out_al + 4*i));
            float d = fabsf(m[sw].x-e.x) + fabsf(m[sw].y-e.y)
                    + fabsf(m[sw].z-e.z) + fabsf(m[sw].w-e.w);
            #pragma unroll
            for (int off = 16; off > 0; off >>= 1) d += __shfl_xor(d, off, 32);
            localmin = fminf(localmin, d);
        }
    }
    red[t] = localmin;
    __syncthreads();
    for (int s2 = 128; s2 > 0; s2 >>= 1) {
        if (t < s2) red[t] = fminf(red[t], red[t + s2]);
        __syncthreads();
    }
    if (t == 0)
        atomicMin((unsigned int*)(ws + WS_LOSS), __float_as_uint(red[0]));
    if (blockIdx.x == 0 && t == 0) {
        float* om = out + OUT_MEM_OFF;
        om[0] = memory[0]; om[1] = memory[1]; om[2] = memory[2];
        om[MEM_ELEMS - 1] = memory[MEM_ELEMS - 1];
    }
}

// ---------------------------------------------------------------------------
// E: write loss; conditional scatter update. 1 block x 256 threads.
__global__ void k_final(const float* __restrict__ x,
                        const int* __restrict__ count,
                        const float* __restrict__ ws,
                        float* __restrict__ d_out) {
    const int t = threadIdx.x;
    const float loss = __uint_as_float(((const unsigned int*)ws)[WS_LOSS]);
    if (t == 0) d_out[0] = loss;
    if (loss <= BETA) {
        unsigned long long key = *(const unsigned long long*)(ws + WS_KEY);
        unsigned int pos = (unsigned int)(key & 0xFFFFFFFFull);
        if (t < CODE_LEN)
            d_out[OUT_MEM_OFF + (size_t)pos * CODE_LEN + t] = ws[WS_ENC + t];
        d_out[OUT_MD_OFF + (size_t)pos * IN_DIM + t] = x[t];
        if (t == 0)
            d_out[OUT_IDX_OFF + pos] = (float)count[0];
    }
}

// ---------------------------------------------------------------------------
extern "C" void kernel_launch(void* const* d_in, const int* in_sizes, int n_in,
                              void* d_out, int out_size, void* d_ws, size_t ws_size,
                              hipStream_t stream) {
    const float* x        = (const float*)d_in[0];
    const float* memory   = (const float*)d_in[1];
    const float* mem_data = (const float*)d_in[2];
    const int*   mem_idx  = (const int*)d_in[3];
    const float* W        = (const float*)d_in[4];
    const float* b        = (const float*)d_in[5];
    const int*   count    = (const int*)d_in[6];
    float* out = (float*)d_out;
    float* ws  = (float*)d_ws;

    k_init<<<1, 64, 0, stream>>>(ws);
    k_stats_enc<<<1088, 256, 0, stream>>>(x, mem_data, mem_idx, W, b, out, ws);
    k_dist_copy<<<1024, 256, 0, stream>>>(memory, out, ws);
    k_final<<<1, 256, 0, stream>>>(x, count, ws, out);
}

// Round 3
// 222.806 us; speedup vs baseline: 1.0246x; 1.0244x over previous
//
#include <hip/hip_runtime.h>
#include <hip/hip_bf16.h>

// Problem constants
#define IN_DIM   256
#define CODE_LEN 128
#define MEM_LEN  65536
#define BETA     1.0f

// Output layout (floats): [0]=loss, [1..]=memory (MEM_LEN*CODE_LEN),
// then mem_data (MEM_LEN*IN_DIM), then mem_idx (MEM_LEN, as float)
#define OUT_MEM_OFF   1
#define OUT_MD_OFF    (1 + MEM_LEN*CODE_LEN)            // 8388609
#define OUT_IDX_OFF   (OUT_MD_OFF + MEM_LEN*IN_DIM)     // 25165825

// Workspace (float indices):
#define WS_COLSUM 0      // float[256]
#define WS_COLSQ  256    // float[256]
#define WS_ENC    512    // float[128]
#define WS_LOSS   640    // uint (init 0xFFFFFFFF)
#define WS_KEY    642    // u64 at byte 2568 (init all-ones)
#define WS_CTR2   644    // uint: stats-kernel completion counter (init 0)

#define MD_ELEMS  (MEM_LEN*IN_DIM)     // 16777216
#define MD_TILES  (MD_ELEMS/4)         // 4194304 aligned source tiles — EXACT
#define MEM_ELEMS (MEM_LEN*CODE_LEN)   // 8388608
#define MEM_TILES (MEM_ELEMS/4)        // 2097152 aligned source tiles — EXACT

// native clang vector type
typedef float vfloat4 __attribute__((ext_vector_type(4)));

// Unaligned (4B-phase) 16-byte store: dst is float* (align 4). clang lowers
// this to an unaligned global_store_dwordx4 (gfx9+ supports misaligned
// global); even if split, the pieces merge in the same L2 lines. Misaligned
// WRITES are cheap (L2 write-combining absorbs them — fillBuffer sustains
// 6.8 TB/s on this very buffer); this lets all LOADS be 16B-aligned dwordx4.
__device__ __forceinline__ void store16u(float* dst, vfloat4 v) {
    __builtin_memcpy(dst, &v, 16);
}

// ---------------------------------------------------------------------------
// init: zero colsum/colsq, set loss/key sentinels, zero completion counter.
__global__ void k_init(float* __restrict__ ws) {
    const int t = threadIdx.x;            // 64 threads
    #pragma unroll
    for (int j = 0; j < 8; ++j) ws[t + j * 64] = 0.f;   // 512 floats
    if (t == 0) {
        ((unsigned int*)ws)[WS_LOSS] = 0xFFFFFFFFu;
        *((unsigned long long*)(ws + WS_KEY)) = ~0ull;
        ((unsigned int*)ws)[WS_CTR2] = 0u;
    }
}

// ---------------------------------------------------------------------------
// A (+enc fold): blocks [0,1024): copy mem_data -> out + per-column sum/sumsq.
//    Source-aligned tiling: tile k = 16B-aligned dwordx4 load of
//    mem_data[4k..4k+3]; store misaligned to out_md+4k. Exact coverage
//    (1024*256*16 == MD_TILES): no bounds checks, no edge fixups.
//    All 16 loads issue into independent registers (no WAR stall on stores),
//    then 16 plain stores + accumulation. Stride 262144 tiles keeps each
//    thread's 4 columns fixed: col base = (4t)&255.
//    blocks [1024,1088): mem_idx copy + packed argmin.
//    Last-finishing block (device-scope counter) computes mean/std -> nrm ->
//    enc = nrm @ W^T + b (former k_enc, bit-identical arithmetic).
__global__ __launch_bounds__(256, 4) void k_stats_enc(
        const float* __restrict__ x,
        const float* __restrict__ mem_data,
        const int*   __restrict__ mem_idx,
        const float* __restrict__ W,
        const float* __restrict__ b,
        float* __restrict__ out,
        float* __restrict__ ws) {
    const int t = threadIdx.x;

    if (blockIdx.x >= 1024) {
        __shared__ unsigned long long red[256];
        const int tid = (blockIdx.x - 1024) * 256 + t;      // 0..16383
        unsigned long long local = ~0ull;
        #pragma unroll
        for (int rep = 0; rep < 4; ++rep) {
            int i = tid + rep * 16384;
            int v = mem_idx[i];
            out[OUT_IDX_OFF + i] = (float)v;
            unsigned long long key =
                (((unsigned long long)(unsigned int)(v ^ (int)0x80000000)) << 32)
                | (unsigned int)i;
            local = local < key ? local : key;
        }
        red[t] = local;
        __syncthreads();
        for (int s = 128; s > 0; s >>= 1) {
            if (t < s) { unsigned long long o = red[t + s]; if (o < red[t]) red[t] = o; }
            __syncthreads();
        }
        if (t == 0) atomicMin((unsigned long long*)(ws + WS_KEY), red[0]);
    } else {
        __shared__ float lsum[256], lsq[256];
        float* __restrict__ out_md = out + OUT_MD_OFF;
        const int t0 = blockIdx.x * 256 + t;                // 0..262143
        float s0=0,s1=0,s2=0,s3=0,q0=0,q1=0,q2=0,q3=0;

        vfloat4 v[16];
        #pragma unroll
        for (int j = 0; j < 16; ++j)
            v[j] = ((const vfloat4*)mem_data)[t0 + j * 262144];   // aligned dwordx4
        #pragma unroll
        for (int j = 0; j < 16; ++j) {
            const int k = t0 + j * 262144;
            store16u(out_md + 4 * k, v[j]);                       // plain, unaligned
            s0 += v[j].x; q0 += v[j].x * v[j].x;
            s1 += v[j].y; q1 += v[j].y * v[j].y;
            s2 += v[j].z; q2 += v[j].z * v[j].z;
            s3 += v[j].w; q3 += v[j].w * v[j].w;
        }

        lsum[t] = 0.f; lsq[t] = 0.f;
        __syncthreads();
        const int c0 = (4 * t) & 255;                       // no wrap: c0 <= 252
        atomicAdd(&lsum[c0    ], s0);  atomicAdd(&lsq[c0    ], q0);
        atomicAdd(&lsum[c0 + 1], s1);  atomicAdd(&lsq[c0 + 1], q1);
        atomicAdd(&lsum[c0 + 2], s2);  atomicAdd(&lsq[c0 + 2], q2);
        atomicAdd(&lsum[c0 + 3], s3);  atomicAdd(&lsq[c0 + 3], q3);
        __syncthreads();
        atomicAdd(&ws[WS_COLSUM + t], lsum[t]);
        atomicAdd(&ws[WS_COLSQ  + t], lsq[t]);
    }

    // ---- completion detection: last of 1088 blocks computes enc ----
    asm volatile("s_waitcnt vmcnt(0)" ::: "memory");  // own stores/atomics drained
    __syncthreads();                                  // whole block drained
    __shared__ unsigned int s_last;
    if (t == 0)
        s_last = (atomicAdd(&((unsigned int*)ws)[WS_CTR2], 1u) == 1087u) ? 1u : 0u;
    __syncthreads();
    if (!s_last) return;

    // ---- former k_enc, bit-identical arithmetic ----
    __shared__ float nrm[IN_DIM];
    {
        // identity atomics = guaranteed-coherent read of the accumulators
        float sum = atomicAdd(&ws[WS_COLSUM + t], 0.0f);
        float sq  = atomicAdd(&ws[WS_COLSQ  + t], 0.0f);
        float mean = sum * (1.0f / MEM_LEN);
        float var  = (sq - sum * sum * (1.0f / MEM_LEN)) * (1.0f / (MEM_LEN - 1));
        var = fmaxf(var, 0.0f);
        float sd = sqrtf(var);
        nrm[t] = (sd == 0.0f) ? 0.0f : (x[t] - mean) / sd;
    }
    __syncthreads();
    if (t < CODE_LEN) {
        float acc = b[t];
        const float* w = W + t * IN_DIM;
        #pragma unroll 8
        for (int d = 0; d < IN_DIM; ++d) acc += nrm[d] * w[d];
        ws[WS_ENC + t] = acc;
    }
}

// ---------------------------------------------------------------------------
// C: memory copy + L1 distance per row + global min.
//    Source-aligned tiling: ONE aligned dwordx4 load per tile serves BOTH the
//    distance math and the (misaligned, plain) store — the old shifted
//    re-load (32 MB of extra L1/L2 reads) and all edge fixups are gone.
//    Exact coverage: 1024*256*8 == MEM_TILES.
//    (Epilogue stays a separate dispatch: its scatter overwrites lines
//    written by other XCDs — the kernel boundary is the cheapest flush.)
__global__ __launch_bounds__(256, 4) void k_dist_copy(
        const float* __restrict__ memory,
        float* __restrict__ out,
        float* __restrict__ ws) {
    __shared__ vfloat4 es[32];
    __shared__ float red[256];
    const int t = threadIdx.x;
    if (t < 32) es[t] = ((const vfloat4*)(ws + WS_ENC))[t];
    __syncthreads();
    const int lane = t & 31;
    const int grp  = t >> 5;
    const vfloat4 e = es[lane];
    float* __restrict__ out_mem = out + OUT_MEM_OFF;   // 4B-aligned only
    float localmin = 3.4e38f;
    #pragma unroll
    for (int half = 0; half < 2; ++half) {
        vfloat4 m[4];
        int idx[4];
        #pragma unroll
        for (int sw = 0; sw < 4; ++sw) {
            const int row = (half * 4 + sw) * 8192 + blockIdx.x * 8 + grp;
            const int i = row * 32 + lane;
            idx[sw] = i;
            m[sw] = ((const vfloat4*)memory)[i];             // aligned dwordx4
        }
        #pragma unroll
        for (int sw = 0; sw < 4; ++sw) {
            const int i = idx[sw];
            store16u(out_mem + 4 * i, m[sw]);                // plain, unaligned
            float d = fabsf(m[sw].x-e.x) + fabsf(m[sw].y-e.y)
                    + fabsf(m[sw].z-e.z) + fabsf(m[sw].w-e.w);
            #pragma unroll
            for (int off = 16; off > 0; off >>= 1) d += __shfl_xor(d, off, 32);
            localmin = fminf(localmin, d);
        }
    }
    red[t] = localmin;
    __syncthreads();
    for (int s2 = 128; s2 > 0; s2 >>= 1) {
        if (t < s2) red[t] = fminf(red[t], red[t + s2]);
        __syncthreads();
    }
    if (t == 0)
        atomicMin((unsigned int*)(ws + WS_LOSS), __float_as_uint(red[0]));
}

// ---------------------------------------------------------------------------
// E: write loss; conditional scatter update. 1 block x 256 threads.
__global__ void k_final(const float* __restrict__ x,
                        const int* __restrict__ count,
                        const float* __restrict__ ws,
                        float* __restrict__ d_out) {
    const int t = threadIdx.x;
    const float loss = __uint_as_float(((const unsigned int*)ws)[WS_LOSS]);
    if (t == 0) d_out[0] = loss;
    if (loss <= BETA) {
        unsigned long long key = *(const unsigned long long*)(ws + WS_KEY);
        unsigned int pos = (unsigned int)(key & 0xFFFFFFFFull);
        if (t < CODE_LEN)
            d_out[OUT_MEM_OFF + (size_t)pos * CODE_LEN + t] = ws[WS_ENC + t];
        d_out[OUT_MD_OFF + (size_t)pos * IN_DIM + t] = x[t];
        if (t == 0)
            d_out[OUT_IDX_OFF + pos] = (float)count[0];
    }
}

// ---------------------------------------------------------------------------
extern "C" void kernel_launch(void* const* d_in, const int* in_sizes, int n_in,
                              void* d_out, int out_size, void* d_ws, size_t ws_size,
                              hipStream_t stream) {
    const float* x        = (const float*)d_in[0];
    const float* memory   = (const float*)d_in[1];
    const float* mem_data = (const float*)d_in[2];
    const int*   mem_idx  = (const int*)d_in[3];
    const float* W        = (const float*)d_in[4];
    const float* b        = (const float*)d_in[5];
    const int*   count    = (const int*)d_in[6];
    float* out = (float*)d_out;
    float* ws  = (float*)d_ws;

    k_init<<<1, 64, 0, stream>>>(ws);
    k_stats_enc<<<1088, 256, 0, stream>>>(x, mem_data, mem_idx, W, b, out, ws);
    k_dist_copy<<<1024, 256, 0, stream>>>(memory, out, ws);
    k_final<<<1, 256, 0, stream>>>(x, count, ws, out);
}